// Round 13
// baseline (31.433 us; speedup 1.0000x reference)
//
#include <hip/hip_runtime.h>
#include <hip/hip_bf16.h>

// Problem constants (from reference)
#define BB 4
#define T1 16
#define T2 32
#define TPn 8
#define Hh 16
#define Kk 64
#define Mm 2049   // 2*H*K + 1
#define NT2B 4    // t2 values handled per block (T2/8)

typedef float  floatx4 __attribute__((ext_vector_type(4)));
typedef int    intx4   __attribute__((ext_vector_type(4)));

// Output: ct_val [B,T1,T2,M,TP] fp32
// ct_val = (dis_sum[b,t1,t2] - dis_sta[b,t1,t2,tp] + dis_cnc[b,t1,t2,m,tp]) / TP
// distance(c1,c2,v) = sgn(c1)*sgn(c2)*(1 - s)*v, s = table[|c1|^|c2|]
// Verified semantics (R3, absmax 3.7e-9): f32 log(x)/log(2) exact at x+1=2^k
// except k=13,15 (one ulp low => floor=k-1):
//   16*(1-s) = __clz(x+1) - 16 + (x==8191 || x==32767)
// Ladder: R6 one-mask WRONG; R7 nt stores regress; R8 fewer blocks regress;
// R9 per-store gathers regress; R10 z=8 champion (27.8); R11 z=16 regress;
// R12 1-barrier preamble + all-active (27.66). R13: grid-dim permutation so
// consecutive blocks write ADJACENT m-chunks (dense instantaneous write
// window -> DRAM page locality), everything else identical to R12.

__device__ __forceinline__ float omss16(int x) {
    int c = __clz(x + 1) - 16;
    if (x == 8191 || x == 32767) c += 1;
    return (float)c;
}

__global__ __launch_bounds__(256)
void critigraph_kernel(const int* __restrict__ sta_loc,   // [B,T1,TP]
                       const int* __restrict__ pos_loc,   // [B,T2,TP]
                       const float* __restrict__ val_n,   // [B,T1,T2]
                       const int* __restrict__ rand_raw,  // [B*T1,H,K,TP]
                       const int* __restrict__ perm,      // [M]
                       float* __restrict__ out)           // [B,T1,T2,M,TP]
{
    const int mc  = blockIdx.x;        // m chunk of 128 (0..15)  [fastest]
    const int t2q = blockIdx.y;        // t2 eighth (0..7), 4 t2 each
    const int bt  = blockIdx.z;        // b*T1 + t1 (0..63)
    const int b   = bt >> 4;           // bt / T1
    const int tid = threadIdx.x;

    __shared__ __align__(16) int   s_pabs[NT2B * TPn];   // |pos|
    __shared__ __align__(16) float s_vs8[NT2B * TPn];    // sgn(pos)*val/8
    __shared__ __align__(16) float s_base8[NT2B * TPn];  // (dis_sum - dis_sta)/8

    // ---- single-phase preamble: lanes 0..31 of wave 0, in-wave 8-lane reduce
    if (tid < NT2B * TPn) {
        const int t2l = tid >> 3;
        const int tp  = tid & 7;
        const int t2  = t2q * NT2B + t2l;
        int pv = pos_loc[(b * T2 + t2) * TPn + tp];
        int pa = pv < 0 ? -pv : pv;
        float psgn = (pv >= 0) ? 1.0f : -1.0f;
        int sv = sta_loc[bt * TPn + tp];
        int sa = sv < 0 ? -sv : sv;
        float ssgn = (sv >= 0) ? 1.0f : -1.0f;
        float v = val_n[bt * T2 + t2];
        float d = ssgn * psgn * (omss16(sa ^ pa) * 0.0625f) * v;
        // 8-lane butterfly sum within each t2 group
        float acc = d;
        acc += __shfl_xor(acc, 1);
        acc += __shfl_xor(acc, 2);
        acc += __shfl_xor(acc, 4);
        s_pabs[tid]  = pa;
        s_vs8[tid]   = psgn * v * 0.125f;
        s_base8[tid] = (acc - d) * 0.125f;
    }
    __syncthreads();

    const int q4 = (tid & 1) * 4;          // which half of the 8 tp's

    // ---- ori quad (wave-uniform base addresses, L1-broadcast)
    int ori_t[4];
    #pragma unroll
    for (int j = 0; j < 4; ++j) {
        int sv = sta_loc[bt * TPn + q4 + j];
        ori_t[j] = sv < 0 ? -sv : sv;
    }

    // ---- main m for this thread (always < 2048, no guard)
    {
        const int m = mc * 128 + (tid >> 1);
        int   a[4];
        float sg16[4];
        const int pm = perm[m];
        if (pm == Hh * Kk) {   // == 1024: the original coordinate
            #pragma unroll
            for (int j = 0; j < 4; ++j) { a[j] = ori_t[j]; sg16[j] = 0.0625f; }
        } else {
            const int r   = (pm < Hh * Kk) ? pm : pm - (Hh * Kk + 1);
            const float ng = (pm < Hh * Kk) ? 0.0625f : -0.0625f;
            const int jj  = r >> 6;           // r / K
            const int k   = r & 63;           // r % K
            const int mb  = (1 << jj) - 1;    // mod 2^jj
            const int flip = 1 << jj;
            const int* rr = rand_raw + ((bt * Hh + jj) * Kk + k) * TPn + q4;
            #pragma unroll
            for (int j = 0; j < 4; ++j) {
                int res = (ori_t[j] ^ flip) ^ (rr[j] & mb);
                a[j] = res;
                sg16[j] = (res == 0) ? 0.0625f : ng;  // sign(+0)=+1
            }
        }

        float* op = out + ((long long)(bt * T2 + t2q * NT2B) * Mm + m) * TPn + q4;
        #pragma unroll
        for (int t2l = 0; t2l < NT2B; ++t2l) {
            const int idx = t2l * TPn + q4;
            const intx4   pv = *(const intx4*)&s_pabs[idx];
            const floatx4 vs = *(const floatx4*)&s_vs8[idx];
            const floatx4 bs = *(const floatx4*)&s_base8[idx];
            floatx4 o;
            o.x = fmaf(omss16(a[0] ^ pv.x) * sg16[0], vs.x, bs.x);
            o.y = fmaf(omss16(a[1] ^ pv.y) * sg16[1], vs.y, bs.y);
            o.z = fmaf(omss16(a[2] ^ pv.z) * sg16[2], vs.z, bs.z);
            o.w = fmaf(omss16(a[3] ^ pv.w) * sg16[3], vs.w, bs.w);
            *(floatx4*)(op + (long long)t2l * (Mm * TPn)) = o;
        }
    }

    // ---- m = 2048 tail: folded into mc==0 blocks, threads 0..1
    if (mc == 0 && tid < 2) {
        const int m = 2048;
        int   a[4];
        float sg16[4];
        const int pm = perm[m];
        if (pm == Hh * Kk) {
            #pragma unroll
            for (int j = 0; j < 4; ++j) { a[j] = ori_t[j]; sg16[j] = 0.0625f; }
        } else {
            const int r   = (pm < Hh * Kk) ? pm : pm - (Hh * Kk + 1);
            const float ng = (pm < Hh * Kk) ? 0.0625f : -0.0625f;
            const int jj  = r >> 6;
            const int k   = r & 63;
            const int mb  = (1 << jj) - 1;
            const int flip = 1 << jj;
            const int* rr = rand_raw + ((bt * Hh + jj) * Kk + k) * TPn + q4;
            #pragma unroll
            for (int j = 0; j < 4; ++j) {
                int res = (ori_t[j] ^ flip) ^ (rr[j] & mb);
                a[j] = res;
                sg16[j] = (res == 0) ? 0.0625f : ng;
            }
        }

        float* op = out + ((long long)(bt * T2 + t2q * NT2B) * Mm + m) * TPn + q4;
        #pragma unroll
        for (int t2l = 0; t2l < NT2B; ++t2l) {
            const int idx = t2l * TPn + q4;
            const intx4   pv = *(const intx4*)&s_pabs[idx];
            const floatx4 vs = *(const floatx4*)&s_vs8[idx];
            const floatx4 bs = *(const floatx4*)&s_base8[idx];
            floatx4 o;
            o.x = fmaf(omss16(a[0] ^ pv.x) * sg16[0], vs.x, bs.x);
            o.y = fmaf(omss16(a[1] ^ pv.y) * sg16[1], vs.y, bs.y);
            o.z = fmaf(omss16(a[2] ^ pv.z) * sg16[2], vs.z, bs.z);
            o.w = fmaf(omss16(a[3] ^ pv.w) * sg16[3], vs.w, bs.w);
            *(floatx4*)(op + (long long)t2l * (Mm * TPn)) = o;
        }
    }
}

extern "C" void kernel_launch(void* const* d_in, const int* in_sizes, int n_in,
                              void* d_out, int out_size, void* d_ws, size_t ws_size,
                              hipStream_t stream) {
    const int*   sta_loc  = (const int*)d_in[0];
    const int*   pos_loc  = (const int*)d_in[1];
    const float* val_n    = (const float*)d_in[2];
    const int*   rand_raw = (const int*)d_in[3];
    const int*   perm     = (const int*)d_in[4];
    float* out = (float*)d_out;

    // x = m-chunk (fastest): consecutive blocks write adjacent 4KB chunks
    dim3 grid(16, 8, BB * T1);   // (16, 8, 64) = 8192 blocks, all active
    critigraph_kernel<<<grid, 256, 0, stream>>>(sta_loc, pos_loc, val_n,
                                                rand_raw, perm, out);
}

// Round 14
// 27.467 us; speedup vs baseline: 1.1444x; 1.1444x over previous
//
#include <hip/hip_runtime.h>
#include <hip/hip_bf16.h>

// Problem constants (from reference)
#define BB 4
#define T1 16
#define T2 32
#define TPn 8
#define Hh 16
#define Kk 64
#define Mm 2049   // 2*H*K + 1
#define NT2B 4    // t2 values handled per block (T2/8)

typedef float  floatx4 __attribute__((ext_vector_type(4)));
typedef int    intx4   __attribute__((ext_vector_type(4)));

// Output: ct_val [B,T1,T2,M,TP] fp32
// ct_val = (dis_sum[b,t1,t2] - dis_sta[b,t1,t2,tp] + dis_cnc[b,t1,t2,m,tp]) / TP
// distance(c1,c2,v) = sgn(c1)*sgn(c2)*(1 - s)*v, s = table[|c1|^|c2|]
// Verified semantics (R3, absmax 3.7e-9): f32 log(x)/log(2) exact at x+1=2^k
// except k=13,15 (one ulp low => floor=k-1):
//   16*(1-s) = __clz(x+1) - 16 + (x==8191 || x==32767)
// Ladder: R6 one-mask WRONG; R7 nt stores regress; R8 fewer blocks regress;
// R9 per-store gathers regress; R10 z=8 champion (27.8); R11 z=16 regress;
// R12 1-barrier preamble + all-active blocks = champion (27.66us, 4.96 TB/s);
// R13 grid permutation (x=mc fastest) regress (31.4) — write-ordering axis
// falsified. This file = R12 champion, reverted.

__device__ __forceinline__ float omss16(int x) {
    int c = __clz(x + 1) - 16;
    if (x == 8191 || x == 32767) c += 1;
    return (float)c;
}

__global__ __launch_bounds__(256)
void critigraph_kernel(const int* __restrict__ sta_loc,   // [B,T1,TP]
                       const int* __restrict__ pos_loc,   // [B,T2,TP]
                       const float* __restrict__ val_n,   // [B,T1,T2]
                       const int* __restrict__ rand_raw,  // [B*T1,H,K,TP]
                       const int* __restrict__ perm,      // [M]
                       float* __restrict__ out)           // [B,T1,T2,M,TP]
{
    const int bt  = blockIdx.x;        // b*T1 + t1
    const int b   = bt >> 4;           // bt / T1
    const int mc  = blockIdx.y;        // m chunk of 128 (0..15)
    const int t2q = blockIdx.z;        // t2 eighth (0..7), 4 t2 each
    const int tid = threadIdx.x;

    __shared__ __align__(16) int   s_pabs[NT2B * TPn];   // |pos|
    __shared__ __align__(16) float s_vs8[NT2B * TPn];    // sgn(pos)*val/8
    __shared__ __align__(16) float s_base8[NT2B * TPn];  // (dis_sum - dis_sta)/8

    // ---- single-phase preamble: lanes 0..31 of wave 0, in-wave 8-lane reduce
    if (tid < NT2B * TPn) {
        const int t2l = tid >> 3;
        const int tp  = tid & 7;
        const int t2  = t2q * NT2B + t2l;
        int pv = pos_loc[(b * T2 + t2) * TPn + tp];
        int pa = pv < 0 ? -pv : pv;
        float psgn = (pv >= 0) ? 1.0f : -1.0f;
        int sv = sta_loc[bt * TPn + tp];
        int sa = sv < 0 ? -sv : sv;
        float ssgn = (sv >= 0) ? 1.0f : -1.0f;
        float v = val_n[bt * T2 + t2];
        float d = ssgn * psgn * (omss16(sa ^ pa) * 0.0625f) * v;
        // 8-lane butterfly sum within each t2 group
        float acc = d;
        acc += __shfl_xor(acc, 1);
        acc += __shfl_xor(acc, 2);
        acc += __shfl_xor(acc, 4);
        s_pabs[tid]  = pa;
        s_vs8[tid]   = psgn * v * 0.125f;
        s_base8[tid] = (acc - d) * 0.125f;
    }
    __syncthreads();

    const int q4 = (tid & 1) * 4;          // which half of the 8 tp's

    // ---- ori quad (wave-uniform base addresses, L1-broadcast)
    int ori_t[4];
    #pragma unroll
    for (int j = 0; j < 4; ++j) {
        int sv = sta_loc[bt * TPn + q4 + j];
        ori_t[j] = sv < 0 ? -sv : sv;
    }

    // ---- main m for this thread (always < 2048, no guard)
    {
        const int m = mc * 128 + (tid >> 1);
        int   a[4];
        float sg16[4];
        const int pm = perm[m];
        if (pm == Hh * Kk) {   // == 1024: the original coordinate
            #pragma unroll
            for (int j = 0; j < 4; ++j) { a[j] = ori_t[j]; sg16[j] = 0.0625f; }
        } else {
            const int r   = (pm < Hh * Kk) ? pm : pm - (Hh * Kk + 1);
            const float ng = (pm < Hh * Kk) ? 0.0625f : -0.0625f;
            const int jj  = r >> 6;           // r / K
            const int k   = r & 63;           // r % K
            const int mb  = (1 << jj) - 1;    // mod 2^jj
            const int flip = 1 << jj;
            const int* rr = rand_raw + ((bt * Hh + jj) * Kk + k) * TPn + q4;
            #pragma unroll
            for (int j = 0; j < 4; ++j) {
                int res = (ori_t[j] ^ flip) ^ (rr[j] & mb);
                a[j] = res;
                sg16[j] = (res == 0) ? 0.0625f : ng;  // sign(+0)=+1
            }
        }

        float* op = out + ((long long)(bt * T2 + t2q * NT2B) * Mm + m) * TPn + q4;
        #pragma unroll
        for (int t2l = 0; t2l < NT2B; ++t2l) {
            const int idx = t2l * TPn + q4;
            const intx4   pv = *(const intx4*)&s_pabs[idx];
            const floatx4 vs = *(const floatx4*)&s_vs8[idx];
            const floatx4 bs = *(const floatx4*)&s_base8[idx];
            floatx4 o;
            o.x = fmaf(omss16(a[0] ^ pv.x) * sg16[0], vs.x, bs.x);
            o.y = fmaf(omss16(a[1] ^ pv.y) * sg16[1], vs.y, bs.y);
            o.z = fmaf(omss16(a[2] ^ pv.z) * sg16[2], vs.z, bs.z);
            o.w = fmaf(omss16(a[3] ^ pv.w) * sg16[3], vs.w, bs.w);
            *(floatx4*)(op + (long long)t2l * (Mm * TPn)) = o;
        }
    }

    // ---- m = 2048 tail: folded into mc==0 blocks, threads 0..1
    if (mc == 0 && tid < 2) {
        const int m = 2048;
        int   a[4];
        float sg16[4];
        const int pm = perm[m];
        if (pm == Hh * Kk) {
            #pragma unroll
            for (int j = 0; j < 4; ++j) { a[j] = ori_t[j]; sg16[j] = 0.0625f; }
        } else {
            const int r   = (pm < Hh * Kk) ? pm : pm - (Hh * Kk + 1);
            const float ng = (pm < Hh * Kk) ? 0.0625f : -0.0625f;
            const int jj  = r >> 6;
            const int k   = r & 63;
            const int mb  = (1 << jj) - 1;
            const int flip = 1 << jj;
            const int* rr = rand_raw + ((bt * Hh + jj) * Kk + k) * TPn + q4;
            #pragma unroll
            for (int j = 0; j < 4; ++j) {
                int res = (ori_t[j] ^ flip) ^ (rr[j] & mb);
                a[j] = res;
                sg16[j] = (res == 0) ? 0.0625f : ng;
            }
        }

        float* op = out + ((long long)(bt * T2 + t2q * NT2B) * Mm + m) * TPn + q4;
        #pragma unroll
        for (int t2l = 0; t2l < NT2B; ++t2l) {
            const int idx = t2l * TPn + q4;
            const intx4   pv = *(const intx4*)&s_pabs[idx];
            const floatx4 vs = *(const floatx4*)&s_vs8[idx];
            const floatx4 bs = *(const floatx4*)&s_base8[idx];
            floatx4 o;
            o.x = fmaf(omss16(a[0] ^ pv.x) * sg16[0], vs.x, bs.x);
            o.y = fmaf(omss16(a[1] ^ pv.y) * sg16[1], vs.y, bs.y);
            o.z = fmaf(omss16(a[2] ^ pv.z) * sg16[2], vs.z, bs.z);
            o.w = fmaf(omss16(a[3] ^ pv.w) * sg16[3], vs.w, bs.w);
            *(floatx4*)(op + (long long)t2l * (Mm * TPn)) = o;
        }
    }
}

extern "C" void kernel_launch(void* const* d_in, const int* in_sizes, int n_in,
                              void* d_out, int out_size, void* d_ws, size_t ws_size,
                              hipStream_t stream) {
    const int*   sta_loc  = (const int*)d_in[0];
    const int*   pos_loc  = (const int*)d_in[1];
    const float* val_n    = (const float*)d_in[2];
    const int*   rand_raw = (const int*)d_in[3];
    const int*   perm     = (const int*)d_in[4];
    float* out = (float*)d_out;

    dim3 grid(BB * T1, 16, 8);   // (64, 16, 8) = 8192 blocks, all active
    critigraph_kernel<<<grid, 256, 0, stream>>>(sta_loc, pos_loc, val_n,
                                                rand_raw, perm, out);
}